// Round 2
// baseline (7920.165 us; speedup 1.0000x reference)
//
#include <hip/hip_runtime.h>
#include <hip/hip_bf16.h>
#include <stdint.h>

#define NPT   16384   // N
#define BB    4
#define SS    1024    // NPOINT
#define KK    32      // NSAMPLE
#define RR    (BB*SS*KK) // 131072 rows
#define C1    67
#define O1    64
#define O3    128
#define EPSF  1e-5f
#define R2F   0.09f   // f32(0.09)
#define FT    512     // FPS threads/block
#define FE    32      // FPS elements/thread

// ---------------- FPS: one block/batch, 512 thr x 32 pts, no spills -----------
__global__ __launch_bounds__(FT, 2) void k_fps(const float* __restrict__ xyz,
                                               int* __restrict__ fps_idx) {
    const int b = blockIdx.x;
    const int tid = threadIdx.x;
    const int lane = tid & 63, wv = tid >> 6;      // 8 waves
    const float* xb = xyz + (size_t)b * 3 * NPT;
    float px[FE], py[FE], pz[FE], dist[FE];
#pragma unroll
    for (int j = 0; j < FE; ++j) {
        int n = j * FT + tid;
        px[j] = xb[n]; py[j] = xb[NPT + n]; pz[j] = xb[2 * NPT + n];
        dist[j] = 1e10f;
    }
    __shared__ uint2 s_red[2][8];
    int p = 0;
    int far = 0;
    float cx = xb[0], cy = xb[NPT], cz = xb[2 * NPT];
    for (int it = 0; it < SS; ++it) {
        if (tid == 0) fps_idx[b * SS + it] = far;
        float bd = -1.0f; int bj = 0;
#pragma unroll
        for (int j = 0; j < FE; ++j) {
            // exact reference arithmetic: (dx*dx + dy*dy) + dz*dz, no FMA
            float dx = __fsub_rn(px[j], cx);
            float dy = __fsub_rn(py[j], cy);
            float dz = __fsub_rn(pz[j], cz);
            float d = __fadd_rn(__fadd_rn(__fmul_rn(dx, dx), __fmul_rn(dy, dy)),
                                __fmul_rn(dz, dz));
            float dj = fminf(dist[j], d);
            dist[j] = dj;
            bool gt = dj > bd;           // strict > keeps lowest j on ties
            bd = gt ? dj : bd;
            bj = gt ? j : bj;
        }
        // pack (dist, index): dist >= 0 so float bits compare monotonically.
        // ~n in low bits -> max key == max dist, ties -> smallest global index.
        int bn = bj * FT + tid;
        unsigned long long key =
            ((unsigned long long)__float_as_uint(bd) << 32) | (unsigned)(~bn);
#pragma unroll
        for (int off = 32; off; off >>= 1) {
            unsigned long long ok = __shfl_xor(key, off);
            if (ok > key) key = ok;
        }
        if (lane == 0) s_red[p][wv] = make_uint2((unsigned)key, (unsigned)(key >> 32));
        __syncthreads();                  // single barrier per iteration
        unsigned long long best = 0;
#pragma unroll
        for (int wq = 0; wq < 8; ++wq) {
            uint2 e = s_red[p][wq];
            unsigned long long k2 = ((unsigned long long)e.y << 32) | e.x;
            if (k2 > best) best = k2;
        }
        far = ~((unsigned)best);
        cx = xb[far]; cy = xb[NPT + far]; cz = xb[2 * NPT + far];
        p ^= 1;                           // double buffer -> WAR-safe w/ 1 barrier
    }
}

// ---------------- gather new_xyz: output0 (B,3,S) + ws copy (b,s,3) ------------
__global__ void k_newxyz(const float* __restrict__ xyz, const int* __restrict__ fps_idx,
                         float* __restrict__ out0, float* __restrict__ nxyz) {
    int g = blockIdx.x * blockDim.x + threadIdx.x;
    if (g >= BB * SS) return;
    int b = g / SS, s = g % SS;
    int id = fps_idx[g];
    const float* xb = xyz + (size_t)b * 3 * NPT;
#pragma unroll
    for (int c = 0; c < 3; ++c) {
        float v = xb[c * NPT + id];
        out0[(size_t)b * 3 * SS + c * SS + s] = v;
        nxyz[g * 3 + c] = v;
    }
}

// ---------------- ball query: one wave per centroid, ballot ranking ------------
__global__ __launch_bounds__(256) void k_ball(const float* __restrict__ xyz,
                                              const float* __restrict__ nxyz,
                                              int* __restrict__ ballidx) {
    int wid = (blockIdx.x * 256 + threadIdx.x) >> 6;   // 0..4095
    int lane = threadIdx.x & 63;
    int b = wid >> 10;
    const float* xb = xyz + (size_t)b * 3 * NPT;
    float nx = nxyz[wid * 3], ny = nxyz[wid * 3 + 1], nz = nxyz[wid * 3 + 2];
    int* out = ballidx + (size_t)wid * KK;
    int cnt = 0;
    int first = -1;
    for (int base = 0; base < NPT; base += 64) {
        int n = base + lane;
        float dx = __fsub_rn(nx, xb[n]);
        float dy = __fsub_rn(ny, xb[NPT + n]);
        float dz = __fsub_rn(nz, xb[2 * NPT + n]);
        float d = __fadd_rn(__fadd_rn(__fmul_rn(dx, dx), __fmul_rn(dy, dy)),
                            __fmul_rn(dz, dz));
        bool hit = !(d > R2F);            // excluded iff sqr > r^2 (matches ref)
        unsigned long long mask = __ballot(hit);
        if (mask) {
            if (first < 0) first = base + __builtin_ctzll(mask);
            int rank = cnt + __popcll(mask & ((1ull << lane) - 1ull));
            if (hit && rank < KK) out[rank] = n;
            cnt += __popcll(mask);
        }
        if (cnt >= KK) break;
    }
    if (lane >= cnt && lane < KK) out[lane] = first;   // pad with first hit
}

// ---------------- transpose pts (B,64,N) -> ptsT (B,N,64) ----------------------
__global__ __launch_bounds__(256) void k_tr(const float* __restrict__ pts,
                                            float* __restrict__ ptsT) {
    __shared__ float t[64][65];
    int b = blockIdx.x >> 8, n0 = (blockIdx.x & 255) << 6;
    const float* pb = pts + (size_t)b * 64 * NPT;
    int tx = threadIdx.x & 63, ty = threadIdx.x >> 6;  // ty in 0..3
#pragma unroll
    for (int k = 0; k < 16; ++k) {
        int c = ty * 16 + k;
        t[c][tx] = pb[(size_t)c * NPT + n0 + tx];      // coalesced in n
    }
    __syncthreads();
#pragma unroll
    for (int k = 0; k < 16; ++k) {
        int n = ty * 16 + k;
        ptsT[((size_t)b * NPT + n0 + n) * 64 + tx] = t[tx][n];  // coalesced in c
    }
}

// ---------------- layer1: gather + GEMM(67->64) + BN partial sums --------------
__global__ __launch_bounds__(256, 4) void k_gemm1(const float* __restrict__ xyz,
        const float* __restrict__ ptsT, const float* __restrict__ nxyz,
        const int* __restrict__ ballidx, const float* __restrict__ w,
        const float* __restrict__ bias, float* __restrict__ Y,
        float* __restrict__ sumP, float* __restrict__ sqP) {
    __shared__ float wlds[C1 * O1];   // [c][o]
    __shared__ float blds[O1];
    __shared__ float lsum[4][O1];
    __shared__ float lsq[4][O1];
    for (int i = threadIdx.x; i < C1 * O1; i += 256) {
        int c = i >> 6, o = i & 63;
        wlds[i] = w[o * C1 + c];
    }
    if (threadIdx.x < O1) blds[threadIdx.x] = bias[threadIdx.x];
    __syncthreads();
    int r = blockIdx.x * 256 + threadIdx.x;
    int b = r >> 15;
    int g = r >> 5;
    int id = ballidx[r];
    const float* xb = xyz + (size_t)b * 3 * NPT;
    float acc[O1];
#pragma unroll
    for (int o = 0; o < O1; ++o) acc[o] = blds[o];
#pragma unroll
    for (int c = 0; c < 3; ++c) {
        float xv = xb[c * NPT + id] - nxyz[g * 3 + c];
        const float* wr = &wlds[c * O1];
#pragma unroll
        for (int o = 0; o < O1; ++o) acc[o] = fmaf(xv, wr[o], acc[o]);
    }
    const float4* p4 = (const float4*)(ptsT + ((size_t)b * NPT + id) * 64);
#pragma unroll
    for (int cc = 0; cc < 16; ++cc) {
        float4 x = p4[cc];
        float xs[4] = {x.x, x.y, x.z, x.w};
#pragma unroll
        for (int u = 0; u < 4; ++u) {
            const float* wr = &wlds[(3 + cc * 4 + u) * O1];
#pragma unroll
            for (int o = 0; o < O1; ++o) acc[o] = fmaf(xs[u], wr[o], acc[o]);
        }
    }
    float* yr = Y + (size_t)r * O1;
#pragma unroll
    for (int o = 0; o < O1; ++o) yr[o] = acc[o];
    int lane = threadIdx.x & 63, wvv = threadIdx.x >> 6;
#pragma unroll
    for (int o = 0; o < O1; ++o) {
        float v = acc[o], v2 = acc[o] * acc[o];
#pragma unroll
        for (int off = 1; off < 64; off <<= 1) { v += __shfl_xor(v, off); v2 += __shfl_xor(v2, off); }
        if (lane == 0) { lsum[wvv][o] = v; lsq[wvv][o] = v2; }
    }
    __syncthreads();
    if (threadIdx.x < O1) {
        int o = threadIdx.x;
        sumP[blockIdx.x * O1 + o] = lsum[0][o] + lsum[1][o] + lsum[2][o] + lsum[3][o];
        sqP[blockIdx.x * O1 + o]  = lsq[0][o] + lsq[1][o] + lsq[2][o] + lsq[3][o];
    }
}

// ---------------- generic MLP layer over precomputed rows ----------------------
// Input rows are RAW previous-layer outputs; NORM_IN applies relu(x*isc+ish).
// WRITE_Y: store raw y. PARTIALS: BN partial sums. POOL: norm+relu+max32 -> out1.
template <int CIN, int COUT, bool NORM_IN, bool WRITE_Y, bool PARTIALS, bool POOL>
__global__ __launch_bounds__(256, (COUT > 64 ? 2 : 4)) void k_mlp(
        const float* __restrict__ Yin, const float* __restrict__ w,
        const float* __restrict__ bias, const float* __restrict__ isc,
        const float* __restrict__ ish, float* __restrict__ Yout,
        float* __restrict__ sumP, float* __restrict__ sqP,
        const float* __restrict__ osc, const float* __restrict__ osh,
        float* __restrict__ out1) {
    __shared__ float wlds[CIN * COUT];   // [c][o]
    __shared__ float blds[COUT];
    __shared__ float iscl[NORM_IN ? CIN : 1], ishl[NORM_IN ? CIN : 1];
    __shared__ float oscl[POOL ? COUT : 1], oshl[POOL ? COUT : 1];
    __shared__ float lsum[PARTIALS ? 4 : 1][PARTIALS ? COUT : 1];
    __shared__ float lsq[PARTIALS ? 4 : 1][PARTIALS ? COUT : 1];
    for (int i = threadIdx.x; i < CIN * COUT; i += 256) {
        int c = i / COUT, o = i % COUT;
        wlds[i] = w[o * CIN + c];
    }
    for (int i = threadIdx.x; i < COUT; i += 256) {
        blds[i] = bias[i];
        if (POOL) { oscl[i] = osc[i]; oshl[i] = osh[i]; }
    }
    if (NORM_IN) {
        for (int i = threadIdx.x; i < CIN; i += 256) { iscl[i] = isc[i]; ishl[i] = ish[i]; }
    }
    __syncthreads();
    int r = blockIdx.x * 256 + threadIdx.x;
    float acc[COUT];
#pragma unroll
    for (int o = 0; o < COUT; ++o) acc[o] = blds[o];
    const float4* r4 = (const float4*)(Yin + (size_t)r * CIN);
#pragma unroll
    for (int cc = 0; cc < CIN / 4; ++cc) {
        float4 x = r4[cc];
        float xs[4] = {x.x, x.y, x.z, x.w};
#pragma unroll
        for (int u = 0; u < 4; ++u) {
            int c = cc * 4 + u;
            float xv = xs[u];
            if (NORM_IN) xv = fmaxf(fmaf(xv, iscl[c], ishl[c]), 0.0f);
            const float* wr = &wlds[c * COUT];
#pragma unroll
            for (int o = 0; o < COUT; ++o) acc[o] = fmaf(xv, wr[o], acc[o]);
        }
    }
    if (WRITE_Y) {
        float* yr = Yout + (size_t)r * COUT;
#pragma unroll
        for (int o = 0; o < COUT; ++o) yr[o] = acc[o];
    }
    if (PARTIALS) {
        int lane = threadIdx.x & 63, wvv = threadIdx.x >> 6;
#pragma unroll
        for (int o = 0; o < COUT; ++o) {
            float v = acc[o], v2 = acc[o] * acc[o];
#pragma unroll
            for (int off = 1; off < 64; off <<= 1) { v += __shfl_xor(v, off); v2 += __shfl_xor(v2, off); }
            if (lane == 0) { lsum[wvv][o] = v; lsq[wvv][o] = v2; }
        }
        __syncthreads();
        if (threadIdx.x < COUT) {
            int o = threadIdx.x;
            sumP[blockIdx.x * COUT + o] = lsum[0][o] + lsum[1][o] + lsum[2][o] + lsum[3][o];
            sqP[blockIdx.x * COUT + o]  = lsq[0][o] + lsq[1][o] + lsq[2][o] + lsq[3][o];
        }
    }
    if (POOL) {
        int b = r >> 15, s = (r >> 5) & (SS - 1);
#pragma unroll
        for (int o = 0; o < COUT; ++o) {
            float v = fmaxf(fmaf(acc[o], oscl[o], oshl[o]), 0.0f);
#pragma unroll
            for (int off = 1; off < 32; off <<= 1) v = fmaxf(v, __shfl_xor(v, off));
            if ((threadIdx.x & 31) == 0)
                out1[((size_t)b * O3 + o) * SS + s] = v;
        }
    }
}

// ---------------- finalize BN stats: 512 partials -> scale/shift ---------------
template <int COUT>
__global__ void k_finalize(const float* __restrict__ sumP, const float* __restrict__ sqP,
                           const float* __restrict__ g, const float* __restrict__ beta,
                           float* __restrict__ scale, float* __restrict__ shift) {
    __shared__ float ls[4][COUT], lq[4][COUT];
    int o = threadIdx.x % COUT, q = threadIdx.x / COUT;
    float s = 0.f, qq = 0.f;
    for (int bk = q; bk < 512; bk += 4) { s += sumP[bk * COUT + o]; qq += sqP[bk * COUT + o]; }
    ls[q][o] = s; lq[q][o] = qq;
    __syncthreads();
    if (q == 0) {
        s  = ls[0][o] + ls[1][o] + ls[2][o] + ls[3][o];
        qq = lq[0][o] + lq[1][o] + lq[2][o] + lq[3][o];
        const float inv = 1.0f / (float)RR;
        float mean = s * inv;
        float var = qq * inv - mean * mean;
        float sc = g[o] * rsqrtf(var + EPSF);
        scale[o] = sc;
        shift[o] = beta[o] - mean * sc;
    }
}

extern "C" void kernel_launch(void* const* d_in, const int* in_sizes, int n_in,
                              void* d_out, int out_size, void* d_ws, size_t ws_size,
                              hipStream_t stream) {
    const float* xyz = (const float*)d_in[0];
    const float* pts = (const float*)d_in[1];
    const float* w1  = (const float*)d_in[2];
    const float* b1  = (const float*)d_in[3];
    const float* g1  = (const float*)d_in[4];
    const float* bt1 = (const float*)d_in[5];
    const float* w2  = (const float*)d_in[6];
    const float* b2  = (const float*)d_in[7];
    const float* g2  = (const float*)d_in[8];
    const float* bt2 = (const float*)d_in[9];
    const float* w3  = (const float*)d_in[10];
    const float* b3  = (const float*)d_in[11];
    const float* g3  = (const float*)d_in[12];
    const float* bt3 = (const float*)d_in[13];
    float* out0 = (float*)d_out;                 // (B,3,S)
    float* out1 = out0 + BB * 3 * SS;            // (B,128,S)

    char* wsb = (char*)d_ws;
    size_t off = 0;
    auto alloc = [&](size_t bytes) {
        char* p = wsb + off;
        off += (bytes + 255) & ~(size_t)255;
        return p;
    };
    int*   fps_idx = (int*)alloc((size_t)BB * SS * 4);
    int*   ballidx = (int*)alloc((size_t)RR * 4);
    float* nxyz    = (float*)alloc((size_t)BB * SS * 3 * 4);
    float* sumP    = (float*)alloc((size_t)512 * 128 * 4);
    float* sqP     = (float*)alloc((size_t)512 * 128 * 4);
    float* sc1     = (float*)alloc(128 * 4);
    float* sh1     = (float*)alloc(128 * 4);
    float* sc2     = (float*)alloc(128 * 4);
    float* sh2     = (float*)alloc(128 * 4);
    float* sc3     = (float*)alloc(128 * 4);
    float* sh3     = (float*)alloc(128 * 4);
    float* Y1      = (float*)alloc((size_t)RR * 64 * 4);
    float* Y2      = (float*)alloc((size_t)RR * 64 * 4);
    float* ptsT    = Y2;   // ptsT (16 MB) lives in Y2's slot; Y2 written after gemm1

    k_tr<<<1024, 256, 0, stream>>>(pts, ptsT);
    k_fps<<<BB, FT, 0, stream>>>(xyz, fps_idx);
    k_newxyz<<<16, 256, 0, stream>>>(xyz, fps_idx, out0, nxyz);
    k_ball<<<1024, 256, 0, stream>>>(xyz, nxyz, ballidx);

    k_gemm1<<<512, 256, 0, stream>>>(xyz, ptsT, nxyz, ballidx, w1, b1, Y1, sumP, sqP);
    k_finalize<64><<<1, 256, 0, stream>>>(sumP, sqP, g1, bt1, sc1, sh1);

    k_mlp<64, 64, true, true, true, false><<<512, 256, 0, stream>>>(
        Y1, w2, b2, sc1, sh1, Y2, sumP, sqP, nullptr, nullptr, nullptr);
    k_finalize<64><<<1, 256, 0, stream>>>(sumP, sqP, g2, bt2, sc2, sh2);

    k_mlp<64, 128, true, false, true, false><<<512, 256, 0, stream>>>(
        Y2, w3, b3, sc2, sh2, nullptr, sumP, sqP, nullptr, nullptr, nullptr);
    k_finalize<128><<<1, 512, 0, stream>>>(sumP, sqP, g3, bt3, sc3, sh3);

    k_mlp<64, 128, true, false, false, true><<<512, 256, 0, stream>>>(
        Y2, w3, b3, sc2, sh2, nullptr, nullptr, nullptr, sc3, sh3, out1);
}

// Round 3
// 7604.129 us; speedup vs baseline: 1.0416x; 1.0416x over previous
//
#include <hip/hip_runtime.h>
#include <hip/hip_bf16.h>
#include <stdint.h>

#define NPT   16384   // N
#define BB    4
#define SS    1024    // NPOINT
#define KK    32      // NSAMPLE
#define RR    (BB*SS*KK) // 131072 rows
#define C1    67
#define O1    64
#define O3    128
#define EPSF  1e-5f
#define R2F   0.09f   // f32(0.09)
#define FT    512     // FPS threads/block
#define FE    32      // FPS elements/thread

// ---------------- FPS: one block/batch, 512 thr x 32 pts, no spills -----------
__global__ __launch_bounds__(FT, 2) void k_fps(const float* __restrict__ xyz,
                                               int* __restrict__ fps_idx) {
    const int b = blockIdx.x;
    const int tid = threadIdx.x;
    const int lane = tid & 63, wv = tid >> 6;      // 8 waves
    const float* xb = xyz + (size_t)b * 3 * NPT;
    float px[FE], py[FE], pz[FE], dist[FE];
#pragma unroll
    for (int j = 0; j < FE; ++j) {
        int n = j * FT + tid;
        px[j] = xb[n]; py[j] = xb[NPT + n]; pz[j] = xb[2 * NPT + n];
        dist[j] = 1e10f;
    }
    __shared__ uint2 s_red[2][8];
    int p = 0;
    int far = 0;
    float cx = xb[0], cy = xb[NPT], cz = xb[2 * NPT];
    for (int it = 0; it < SS; ++it) {
        if (tid == 0) fps_idx[b * SS + it] = far;
        float bd = -1.0f; int bj = 0;
#pragma unroll
        for (int j = 0; j < FE; ++j) {
            // exact reference arithmetic: (dx*dx + dy*dy) + dz*dz, no FMA
            float dx = __fsub_rn(px[j], cx);
            float dy = __fsub_rn(py[j], cy);
            float dz = __fsub_rn(pz[j], cz);
            float d = __fadd_rn(__fadd_rn(__fmul_rn(dx, dx), __fmul_rn(dy, dy)),
                                __fmul_rn(dz, dz));
            float dj = fminf(dist[j], d);
            dist[j] = dj;
            bool gt = dj > bd;           // strict > keeps lowest j on ties
            bd = gt ? dj : bd;
            bj = gt ? j : bj;
        }
        // pack (dist, index): dist >= 0 so float bits compare monotonically.
        // ~n in low bits -> max key == max dist, ties -> smallest global index.
        int bn = bj * FT + tid;
        unsigned long long key =
            ((unsigned long long)__float_as_uint(bd) << 32) | (unsigned)(~bn);
#pragma unroll
        for (int off = 32; off; off >>= 1) {
            unsigned long long ok = __shfl_xor(key, off);
            if (ok > key) key = ok;
        }
        if (lane == 0) s_red[p][wv] = make_uint2((unsigned)key, (unsigned)(key >> 32));
        __syncthreads();                  // single barrier per iteration
        unsigned long long best = 0;
#pragma unroll
        for (int wq = 0; wq < 8; ++wq) {
            uint2 e = s_red[p][wq];
            unsigned long long k2 = ((unsigned long long)e.y << 32) | e.x;
            if (k2 > best) best = k2;
        }
        far = ~((unsigned)best);
        cx = xb[far]; cy = xb[NPT + far]; cz = xb[2 * NPT + far];
        p ^= 1;                           // double buffer -> WAR-safe w/ 1 barrier
    }
}

// ---------------- gather new_xyz: output0 (B,3,S) + ws copy (b,s,3) ------------
__global__ void k_newxyz(const float* __restrict__ xyz, const int* __restrict__ fps_idx,
                         float* __restrict__ out0, float* __restrict__ nxyz) {
    int g = blockIdx.x * blockDim.x + threadIdx.x;
    if (g >= BB * SS) return;
    int b = g / SS, s = g % SS;
    int id = fps_idx[g];
    const float* xb = xyz + (size_t)b * 3 * NPT;
#pragma unroll
    for (int c = 0; c < 3; ++c) {
        float v = xb[c * NPT + id];
        out0[(size_t)b * 3 * SS + c * SS + s] = v;
        nxyz[g * 3 + c] = v;
    }
}

// ---------------- ball query: one wave per centroid, ballot ranking ------------
__global__ __launch_bounds__(256) void k_ball(const float* __restrict__ xyz,
                                              const float* __restrict__ nxyz,
                                              int* __restrict__ ballidx) {
    int wid = (blockIdx.x * 256 + threadIdx.x) >> 6;   // 0..4095
    int lane = threadIdx.x & 63;
    int b = wid >> 10;
    const float* xb = xyz + (size_t)b * 3 * NPT;
    float nx = nxyz[wid * 3], ny = nxyz[wid * 3 + 1], nz = nxyz[wid * 3 + 2];
    int* out = ballidx + (size_t)wid * KK;
    int cnt = 0;
    int first = -1;
    for (int base = 0; base < NPT; base += 64) {
        int n = base + lane;
        float dx = __fsub_rn(nx, xb[n]);
        float dy = __fsub_rn(ny, xb[NPT + n]);
        float dz = __fsub_rn(nz, xb[2 * NPT + n]);
        float d = __fadd_rn(__fadd_rn(__fmul_rn(dx, dx), __fmul_rn(dy, dy)),
                            __fmul_rn(dz, dz));
        bool hit = !(d > R2F);            // excluded iff sqr > r^2 (matches ref)
        unsigned long long mask = __ballot(hit);
        if (mask) {
            if (first < 0) first = base + __builtin_ctzll(mask);
            int rank = cnt + __popcll(mask & ((1ull << lane) - 1ull));
            if (hit && rank < KK) out[rank] = n;
            cnt += __popcll(mask);
        }
        if (cnt >= KK) break;
    }
    if (lane >= cnt && lane < KK) out[lane] = first;   // pad with first hit
}

// ---------------- transpose pts (B,64,N) -> ptsT (B,N,64) ----------------------
__global__ __launch_bounds__(256) void k_tr(const float* __restrict__ pts,
                                            float* __restrict__ ptsT) {
    __shared__ float t[64][65];
    int b = blockIdx.x >> 8, n0 = (blockIdx.x & 255) << 6;
    const float* pb = pts + (size_t)b * 64 * NPT;
    int tx = threadIdx.x & 63, ty = threadIdx.x >> 6;  // ty in 0..3
#pragma unroll
    for (int k = 0; k < 16; ++k) {
        int c = ty * 16 + k;
        t[c][tx] = pb[(size_t)c * NPT + n0 + tx];      // coalesced in n
    }
    __syncthreads();
#pragma unroll
    for (int k = 0; k < 16; ++k) {
        int n = ty * 16 + k;
        ptsT[((size_t)b * NPT + n0 + n) * 64 + tx] = t[tx][n];  // coalesced in c
    }
}

// ---------------- layer1: gather + GEMM(67->64) + BN partial sums --------------
__global__ __launch_bounds__(256, 4) void k_gemm1(const float* __restrict__ xyz,
        const float* __restrict__ ptsT, const float* __restrict__ nxyz,
        const int* __restrict__ ballidx, const float* __restrict__ w,
        const float* __restrict__ bias, float* __restrict__ Y,
        float* __restrict__ sumP, float* __restrict__ sqP) {
    __shared__ float wlds[C1 * O1];   // [c][o]
    __shared__ float blds[O1];
    __shared__ float lsum[4][O1];
    __shared__ float lsq[4][O1];
    for (int i = threadIdx.x; i < C1 * O1; i += 256) {
        int c = i >> 6, o = i & 63;
        wlds[i] = w[o * C1 + c];
    }
    if (threadIdx.x < O1) blds[threadIdx.x] = bias[threadIdx.x];
    __syncthreads();
    int r = blockIdx.x * 256 + threadIdx.x;
    int b = r >> 15;
    int g = r >> 5;
    int id = ballidx[r];
    const float* xb = xyz + (size_t)b * 3 * NPT;
    float acc[O1];
#pragma unroll
    for (int o = 0; o < O1; ++o) acc[o] = blds[o];
#pragma unroll
    for (int c = 0; c < 3; ++c) {
        float xv = xb[c * NPT + id] - nxyz[g * 3 + c];
        const float* wr = &wlds[c * O1];
#pragma unroll
        for (int o = 0; o < O1; ++o) acc[o] = fmaf(xv, wr[o], acc[o]);
    }
    const float4* p4 = (const float4*)(ptsT + ((size_t)b * NPT + id) * 64);
#pragma unroll
    for (int cc = 0; cc < 16; ++cc) {
        float4 x = p4[cc];
        float xs[4] = {x.x, x.y, x.z, x.w};
#pragma unroll
        for (int u = 0; u < 4; ++u) {
            const float* wr = &wlds[(3 + cc * 4 + u) * O1];
#pragma unroll
            for (int o = 0; o < O1; ++o) acc[o] = fmaf(xs[u], wr[o], acc[o]);
        }
    }
    float4* yr = (float4*)(Y + (size_t)r * O1);
#pragma unroll
    for (int o4 = 0; o4 < O1 / 4; ++o4)
        yr[o4] = make_float4(acc[o4 * 4], acc[o4 * 4 + 1], acc[o4 * 4 + 2], acc[o4 * 4 + 3]);
    int lane = threadIdx.x & 63, wvv = threadIdx.x >> 6;
#pragma unroll
    for (int o = 0; o < O1; ++o) {
        float v = acc[o], v2 = acc[o] * acc[o];
#pragma unroll
        for (int off = 1; off < 64; off <<= 1) { v += __shfl_xor(v, off); v2 += __shfl_xor(v2, off); }
        if (lane == 0) { lsum[wvv][o] = v; lsq[wvv][o] = v2; }
    }
    __syncthreads();
    if (threadIdx.x < O1) {
        int o = threadIdx.x;
        sumP[blockIdx.x * O1 + o] = lsum[0][o] + lsum[1][o] + lsum[2][o] + lsum[3][o];
        sqP[blockIdx.x * O1 + o]  = lsq[0][o] + lsq[1][o] + lsq[2][o] + lsq[3][o];
    }
}

// ---------------- generic MLP layer: 64 outputs PER BLOCK (no spills) ----------
// OTOT total outputs; blockIdx.y selects which 64-wide half this block computes.
// NORM_IN applies relu(x*isc+ish) to input rows. WRITE_Y stores raw y (OTOT=64
// only). PARTIALS: BN partial sums into sumP[bid][OTOT]. POOL: norm+relu+max32.
template <int CIN, int OTOT, bool NORM_IN, bool WRITE_Y, bool PARTIALS, bool POOL>
__global__ __launch_bounds__(256, 4) void k_mlp(
        const float* __restrict__ Yin, const float* __restrict__ w,
        const float* __restrict__ bias, const float* __restrict__ isc,
        const float* __restrict__ ish, float* __restrict__ Yout,
        float* __restrict__ sumP, float* __restrict__ sqP,
        const float* __restrict__ osc, const float* __restrict__ osh,
        float* __restrict__ out1) {
    const int h = blockIdx.y;            // 64-wide output half (0 or OTOT/64-1)
    const int ob = h * 64;               // output base
    __shared__ float wlds[CIN * 64];     // [c][o] for this half
    __shared__ float blds[64];
    __shared__ float iscl[NORM_IN ? CIN : 1], ishl[NORM_IN ? CIN : 1];
    __shared__ float oscl[POOL ? 64 : 1], oshl[POOL ? 64 : 1];
    __shared__ float lsum[PARTIALS ? 4 : 1][PARTIALS ? 64 : 1];
    __shared__ float lsq[PARTIALS ? 4 : 1][PARTIALS ? 64 : 1];
    for (int i = threadIdx.x; i < CIN * 64; i += 256) {
        int c = i >> 6, o = i & 63;
        wlds[i] = w[(ob + o) * CIN + c];
    }
    if (threadIdx.x < 64) {
        int o = threadIdx.x;
        blds[o] = bias[ob + o];
        if (POOL) { oscl[o] = osc[ob + o]; oshl[o] = osh[ob + o]; }
    }
    if (NORM_IN) {
        for (int i = threadIdx.x; i < CIN; i += 256) { iscl[i] = isc[i]; ishl[i] = ish[i]; }
    }
    __syncthreads();
    int r = blockIdx.x * 256 + threadIdx.x;
    float acc[64];
#pragma unroll
    for (int o = 0; o < 64; ++o) acc[o] = blds[o];
    const float4* r4 = (const float4*)(Yin + (size_t)r * CIN);
#pragma unroll
    for (int cc = 0; cc < CIN / 4; ++cc) {
        float4 x = r4[cc];
        float xs[4] = {x.x, x.y, x.z, x.w};
#pragma unroll
        for (int u = 0; u < 4; ++u) {
            int c = cc * 4 + u;
            float xv = xs[u];
            if (NORM_IN) xv = fmaxf(fmaf(xv, iscl[c], ishl[c]), 0.0f);
            const float* wr = &wlds[c * 64];
#pragma unroll
            for (int o = 0; o < 64; ++o) acc[o] = fmaf(xv, wr[o], acc[o]);
        }
    }
    if (WRITE_Y) {
        float4* yr = (float4*)(Yout + (size_t)r * OTOT + ob);
#pragma unroll
        for (int o4 = 0; o4 < 16; ++o4)
            yr[o4] = make_float4(acc[o4 * 4], acc[o4 * 4 + 1], acc[o4 * 4 + 2], acc[o4 * 4 + 3]);
    }
    if (PARTIALS) {
        int lane = threadIdx.x & 63, wvv = threadIdx.x >> 6;
#pragma unroll
        for (int o = 0; o < 64; ++o) {
            float v = acc[o], v2 = acc[o] * acc[o];
#pragma unroll
            for (int off = 1; off < 64; off <<= 1) { v += __shfl_xor(v, off); v2 += __shfl_xor(v2, off); }
            if (lane == 0) { lsum[wvv][o] = v; lsq[wvv][o] = v2; }
        }
        __syncthreads();
        if (threadIdx.x < 64) {
            int o = threadIdx.x;
            sumP[blockIdx.x * OTOT + ob + o] = lsum[0][o] + lsum[1][o] + lsum[2][o] + lsum[3][o];
            sqP[blockIdx.x * OTOT + ob + o]  = lsq[0][o] + lsq[1][o] + lsq[2][o] + lsq[3][o];
        }
    }
    if (POOL) {
        int b = r >> 15, s = (r >> 5) & (SS - 1);
#pragma unroll
        for (int o = 0; o < 64; ++o) {
            float v = fmaxf(fmaf(acc[o], oscl[o], oshl[o]), 0.0f);
#pragma unroll
            for (int off = 1; off < 32; off <<= 1) v = fmaxf(v, __shfl_xor(v, off));
            if ((threadIdx.x & 31) == 0)
                out1[((size_t)b * O3 + ob + o) * SS + s] = v;
        }
    }
}

// ---------------- finalize BN stats: 512 partials -> scale/shift ---------------
template <int COUT>
__global__ void k_finalize(const float* __restrict__ sumP, const float* __restrict__ sqP,
                           const float* __restrict__ g, const float* __restrict__ beta,
                           float* __restrict__ scale, float* __restrict__ shift) {
    __shared__ float ls[4][COUT], lq[4][COUT];
    int o = threadIdx.x % COUT, q = threadIdx.x / COUT;
    float s = 0.f, qq = 0.f;
    for (int bk = q; bk < 512; bk += 4) { s += sumP[bk * COUT + o]; qq += sqP[bk * COUT + o]; }
    ls[q][o] = s; lq[q][o] = qq;
    __syncthreads();
    if (q == 0) {
        s  = ls[0][o] + ls[1][o] + ls[2][o] + ls[3][o];
        qq = lq[0][o] + lq[1][o] + lq[2][o] + lq[3][o];
        const float inv = 1.0f / (float)RR;
        float mean = s * inv;
        float var = qq * inv - mean * mean;
        float sc = g[o] * rsqrtf(var + EPSF);
        scale[o] = sc;
        shift[o] = beta[o] - mean * sc;
    }
}

extern "C" void kernel_launch(void* const* d_in, const int* in_sizes, int n_in,
                              void* d_out, int out_size, void* d_ws, size_t ws_size,
                              hipStream_t stream) {
    const float* xyz = (const float*)d_in[0];
    const float* pts = (const float*)d_in[1];
    const float* w1  = (const float*)d_in[2];
    const float* b1  = (const float*)d_in[3];
    const float* g1  = (const float*)d_in[4];
    const float* bt1 = (const float*)d_in[5];
    const float* w2  = (const float*)d_in[6];
    const float* b2  = (const float*)d_in[7];
    const float* g2  = (const float*)d_in[8];
    const float* bt2 = (const float*)d_in[9];
    const float* w3  = (const float*)d_in[10];
    const float* b3  = (const float*)d_in[11];
    const float* g3  = (const float*)d_in[12];
    const float* bt3 = (const float*)d_in[13];
    float* out0 = (float*)d_out;                 // (B,3,S)
    float* out1 = out0 + BB * 3 * SS;            // (B,128,S)

    char* wsb = (char*)d_ws;
    size_t off = 0;
    auto alloc = [&](size_t bytes) {
        char* p = wsb + off;
        off += (bytes + 255) & ~(size_t)255;
        return p;
    };
    int*   fps_idx = (int*)alloc((size_t)BB * SS * 4);
    int*   ballidx = (int*)alloc((size_t)RR * 4);
    float* nxyz    = (float*)alloc((size_t)BB * SS * 3 * 4);
    float* sumP    = (float*)alloc((size_t)512 * 128 * 4);
    float* sqP     = (float*)alloc((size_t)512 * 128 * 4);
    float* sc1     = (float*)alloc(128 * 4);
    float* sh1     = (float*)alloc(128 * 4);
    float* sc2     = (float*)alloc(128 * 4);
    float* sh2     = (float*)alloc(128 * 4);
    float* sc3     = (float*)alloc(128 * 4);
    float* sh3     = (float*)alloc(128 * 4);
    float* Y1      = (float*)alloc((size_t)RR * 64 * 4);
    float* Y2      = (float*)alloc((size_t)RR * 64 * 4);
    float* ptsT    = Y2;   // ptsT (16 MB) lives in Y2's slot; Y2 written after gemm1

    k_tr<<<1024, 256, 0, stream>>>(pts, ptsT);
    k_fps<<<BB, FT, 0, stream>>>(xyz, fps_idx);
    k_newxyz<<<16, 256, 0, stream>>>(xyz, fps_idx, out0, nxyz);
    k_ball<<<1024, 256, 0, stream>>>(xyz, nxyz, ballidx);

    k_gemm1<<<512, 256, 0, stream>>>(xyz, ptsT, nxyz, ballidx, w1, b1, Y1, sumP, sqP);
    k_finalize<64><<<1, 256, 0, stream>>>(sumP, sqP, g1, bt1, sc1, sh1);

    k_mlp<64, 64, true, true, true, false><<<dim3(512, 1), 256, 0, stream>>>(
        Y1, w2, b2, sc1, sh1, Y2, sumP, sqP, nullptr, nullptr, nullptr);
    k_finalize<64><<<1, 256, 0, stream>>>(sumP, sqP, g2, bt2, sc2, sh2);

    k_mlp<64, 128, true, false, true, false><<<dim3(512, 2), 256, 0, stream>>>(
        Y2, w3, b3, sc2, sh2, nullptr, sumP, sqP, nullptr, nullptr, nullptr);
    k_finalize<128><<<1, 512, 0, stream>>>(sumP, sqP, g3, bt3, sc3, sh3);

    k_mlp<64, 128, true, false, false, true><<<dim3(512, 2), 256, 0, stream>>>(
        Y2, w3, b3, sc2, sh2, nullptr, nullptr, nullptr, sc3, sh3, out1);
}

// Round 4
// 2327.675 us; speedup vs baseline: 3.4026x; 3.2668x over previous
//
#include <hip/hip_runtime.h>
#include <hip/hip_bf16.h>
#include <stdint.h>

#define NPT   16384   // N
#define BB    4
#define SS    1024    // NPOINT
#define KK    32      // NSAMPLE
#define RR    (BB*SS*KK) // 131072 rows
#define C1    67
#define O1    64
#define O3    128
#define EPSF  1e-5f
#define R2F   0.09f   // f32(0.09)
#define FT    512     // FPS threads/block
#define FE    32      // FPS elements/thread

// ---------------- FPS: one block/batch, 512 thr x 32 pts ----------------------
// waves_per_eu(1,2): tell the allocator NOT to chase >2 waves/EU, so the
// ~150 live registers (px/py/pz/dist[32]) get real VGPRs instead of being
// spilled/re-loaded (round-3: VGPR=84 -> pathological scratch traffic).
__global__ __launch_bounds__(FT)
__attribute__((amdgpu_waves_per_eu(1, 2)))
void k_fps(const float* __restrict__ xyz, int* __restrict__ fps_idx) {
    const int b = blockIdx.x;
    const int tid = threadIdx.x;
    const int lane = tid & 63, wv = tid >> 6;      // 8 waves
    const float* xb = xyz + (size_t)b * 3 * NPT;
    float px[FE], py[FE], pz[FE], dist[FE];
#pragma unroll
    for (int j = 0; j < FE; ++j) {
        int n = j * FT + tid;
        px[j] = xb[n]; py[j] = xb[NPT + n]; pz[j] = xb[2 * NPT + n];
        dist[j] = 1e10f;
    }
    __shared__ uint2 s_red[2][8];
    int p = 0;
    int far = 0;
    float cx = xb[0], cy = xb[NPT], cz = xb[2 * NPT];
    for (int it = 0; it < SS; ++it) {
        if (tid == 0) fps_idx[b * SS + it] = far;
        float bd = -1.0f; int bj = 0;
#pragma unroll
        for (int j = 0; j < FE; ++j) {
            // exact reference arithmetic: (dx*dx + dy*dy) + dz*dz, no FMA
            float dx = __fsub_rn(px[j], cx);
            float dy = __fsub_rn(py[j], cy);
            float dz = __fsub_rn(pz[j], cz);
            float d = __fadd_rn(__fadd_rn(__fmul_rn(dx, dx), __fmul_rn(dy, dy)),
                                __fmul_rn(dz, dz));
            float dj = fminf(dist[j], d);
            dist[j] = dj;
            bool gt = dj > bd;           // strict > keeps lowest j on ties
            bd = gt ? dj : bd;
            bj = gt ? j : bj;
        }
        // pack (dist, index): dist >= 0 so float bits compare monotonically.
        // ~n in low bits -> max key == max dist, ties -> smallest global index.
        int bn = bj * FT + tid;
        unsigned long long key =
            ((unsigned long long)__float_as_uint(bd) << 32) | (unsigned)(~bn);
#pragma unroll
        for (int off = 32; off; off >>= 1) {
            unsigned long long ok = __shfl_xor(key, off);
            if (ok > key) key = ok;
        }
        if (lane == 0) s_red[p][wv] = make_uint2((unsigned)key, (unsigned)(key >> 32));
        __syncthreads();                  // single barrier per iteration
        unsigned long long best = 0;
#pragma unroll
        for (int wq = 0; wq < 8; ++wq) {
            uint2 e = s_red[p][wq];
            unsigned long long k2 = ((unsigned long long)e.y << 32) | e.x;
            if (k2 > best) best = k2;
        }
        far = ~((unsigned)best);
        cx = xb[far]; cy = xb[NPT + far]; cz = xb[2 * NPT + far];
        p ^= 1;                           // double buffer -> WAR-safe w/ 1 barrier
    }
}

// ---------------- gather new_xyz: output0 (B,3,S) + ws copy (b,s,3) ------------
__global__ void k_newxyz(const float* __restrict__ xyz, const int* __restrict__ fps_idx,
                         float* __restrict__ out0, float* __restrict__ nxyz) {
    int g = blockIdx.x * blockDim.x + threadIdx.x;
    if (g >= BB * SS) return;
    int b = g / SS, s = g % SS;
    int id = fps_idx[g];
    const float* xb = xyz + (size_t)b * 3 * NPT;
#pragma unroll
    for (int c = 0; c < 3; ++c) {
        float v = xb[c * NPT + id];
        out0[(size_t)b * 3 * SS + c * SS + s] = v;
        nxyz[g * 3 + c] = v;
    }
}

// ---------------- ball query: one wave per centroid, ballot ranking ------------
__global__ __launch_bounds__(256) void k_ball(const float* __restrict__ xyz,
                                              const float* __restrict__ nxyz,
                                              int* __restrict__ ballidx) {
    int wid = (blockIdx.x * 256 + threadIdx.x) >> 6;   // 0..4095
    int lane = threadIdx.x & 63;
    int b = wid >> 10;
    const float* xb = xyz + (size_t)b * 3 * NPT;
    float nx = nxyz[wid * 3], ny = nxyz[wid * 3 + 1], nz = nxyz[wid * 3 + 2];
    int* out = ballidx + (size_t)wid * KK;
    int cnt = 0;
    int first = -1;
    for (int base = 0; base < NPT; base += 64) {
        int n = base + lane;
        float dx = __fsub_rn(nx, xb[n]);
        float dy = __fsub_rn(ny, xb[NPT + n]);
        float dz = __fsub_rn(nz, xb[2 * NPT + n]);
        float d = __fadd_rn(__fadd_rn(__fmul_rn(dx, dx), __fmul_rn(dy, dy)),
                            __fmul_rn(dz, dz));
        bool hit = !(d > R2F);            // excluded iff sqr > r^2 (matches ref)
        unsigned long long mask = __ballot(hit);
        if (mask) {
            if (first < 0) first = base + __builtin_ctzll(mask);
            int rank = cnt + __popcll(mask & ((1ull << lane) - 1ull));
            if (hit && rank < KK) out[rank] = n;
            cnt += __popcll(mask);
        }
        if (cnt >= KK) break;
    }
    if (lane >= cnt && lane < KK) out[lane] = first;   // pad with first hit
}

// ---------------- transpose pts (B,64,N) -> ptsT (B,N,64) ----------------------
__global__ __launch_bounds__(256) void k_tr(const float* __restrict__ pts,
                                            float* __restrict__ ptsT) {
    __shared__ float t[64][65];
    int b = blockIdx.x >> 8, n0 = (blockIdx.x & 255) << 6;
    const float* pb = pts + (size_t)b * 64 * NPT;
    int tx = threadIdx.x & 63, ty = threadIdx.x >> 6;  // ty in 0..3
#pragma unroll
    for (int k = 0; k < 16; ++k) {
        int c = ty * 16 + k;
        t[c][tx] = pb[(size_t)c * NPT + n0 + tx];      // coalesced in n
    }
    __syncthreads();
#pragma unroll
    for (int k = 0; k < 16; ++k) {
        int n = ty * 16 + k;
        ptsT[((size_t)b * NPT + n0 + n) * 64 + tx] = t[tx][n];  // coalesced in c
    }
}

// ---------------- layer1: gather + GEMM(67->64) + BN partial sums --------------
// Plain launch_bounds(256) + waves_per_eu(1,4): allocator may use up to
// 128+ VGPRs (acc[64] + weight broadcast regs ~ 110 live) without spilling.
__global__ __launch_bounds__(256)
__attribute__((amdgpu_waves_per_eu(1, 4)))
void k_gemm1(const float* __restrict__ xyz,
        const float* __restrict__ ptsT, const float* __restrict__ nxyz,
        const int* __restrict__ ballidx, const float* __restrict__ w,
        const float* __restrict__ bias, float* __restrict__ Y,
        float* __restrict__ sumP, float* __restrict__ sqP) {
    __shared__ float wlds[C1 * O1];   // [c][o]
    __shared__ float blds[O1];
    __shared__ float lsum[4][O1];
    __shared__ float lsq[4][O1];
    for (int i = threadIdx.x; i < C1 * O1; i += 256) {
        int c = i >> 6, o = i & 63;
        wlds[i] = w[o * C1 + c];
    }
    if (threadIdx.x < O1) blds[threadIdx.x] = bias[threadIdx.x];
    __syncthreads();
    int r = blockIdx.x * 256 + threadIdx.x;
    int b = r >> 15;
    int g = r >> 5;
    int id = ballidx[r];
    const float* xb = xyz + (size_t)b * 3 * NPT;
    float acc[O1];
#pragma unroll
    for (int o = 0; o < O1; ++o) acc[o] = blds[o];
#pragma unroll
    for (int c = 0; c < 3; ++c) {
        float xv = xb[c * NPT + id] - nxyz[g * 3 + c];
        const float* wr = &wlds[c * O1];
#pragma unroll
        for (int o = 0; o < O1; ++o) acc[o] = fmaf(xv, wr[o], acc[o]);
    }
    const float4* p4 = (const float4*)(ptsT + ((size_t)b * NPT + id) * 64);
#pragma unroll 4
    for (int cc = 0; cc < 16; ++cc) {
        float4 x = p4[cc];
        float xs[4] = {x.x, x.y, x.z, x.w};
#pragma unroll
        for (int u = 0; u < 4; ++u) {
            const float* wr = &wlds[(3 + cc * 4 + u) * O1];
#pragma unroll
            for (int o = 0; o < O1; ++o) acc[o] = fmaf(xs[u], wr[o], acc[o]);
        }
    }
    float4* yr = (float4*)(Y + (size_t)r * O1);
#pragma unroll
    for (int o4 = 0; o4 < O1 / 4; ++o4)
        yr[o4] = make_float4(acc[o4 * 4], acc[o4 * 4 + 1], acc[o4 * 4 + 2], acc[o4 * 4 + 3]);
    int lane = threadIdx.x & 63, wvv = threadIdx.x >> 6;
#pragma unroll
    for (int o = 0; o < O1; ++o) {
        float v = acc[o], v2 = acc[o] * acc[o];
#pragma unroll
        for (int off = 1; off < 64; off <<= 1) { v += __shfl_xor(v, off); v2 += __shfl_xor(v2, off); }
        if (lane == 0) { lsum[wvv][o] = v; lsq[wvv][o] = v2; }
    }
    __syncthreads();
    if (threadIdx.x < O1) {
        int o = threadIdx.x;
        sumP[blockIdx.x * O1 + o] = lsum[0][o] + lsum[1][o] + lsum[2][o] + lsum[3][o];
        sqP[blockIdx.x * O1 + o]  = lsq[0][o] + lsq[1][o] + lsq[2][o] + lsq[3][o];
    }
}

// ---------------- generic MLP layer: 64 outputs PER BLOCK ----------------------
// OTOT total outputs; blockIdx.y selects which 64-wide half this block computes.
// NORM_IN applies relu(x*isc+ish) to input rows. WRITE_Y stores raw y (OTOT=64
// only). PARTIALS: BN partial sums into sumP[bid][OTOT]. POOL: norm+relu+max32.
template <int CIN, int OTOT, bool NORM_IN, bool WRITE_Y, bool PARTIALS, bool POOL>
__global__ __launch_bounds__(256)
__attribute__((amdgpu_waves_per_eu(1, 4)))
void k_mlp(
        const float* __restrict__ Yin, const float* __restrict__ w,
        const float* __restrict__ bias, const float* __restrict__ isc,
        const float* __restrict__ ish, float* __restrict__ Yout,
        float* __restrict__ sumP, float* __restrict__ sqP,
        const float* __restrict__ osc, const float* __restrict__ osh,
        float* __restrict__ out1) {
    const int h = blockIdx.y;            // 64-wide output half (0 or OTOT/64-1)
    const int ob = h * 64;               // output base
    __shared__ float wlds[CIN * 64];     // [c][o] for this half
    __shared__ float blds[64];
    __shared__ float iscl[NORM_IN ? CIN : 1], ishl[NORM_IN ? CIN : 1];
    __shared__ float oscl[POOL ? 64 : 1], oshl[POOL ? 64 : 1];
    __shared__ float lsum[PARTIALS ? 4 : 1][PARTIALS ? 64 : 1];
    __shared__ float lsq[PARTIALS ? 4 : 1][PARTIALS ? 64 : 1];
    for (int i = threadIdx.x; i < CIN * 64; i += 256) {
        int c = i >> 6, o = i & 63;
        wlds[i] = w[(ob + o) * CIN + c];
    }
    if (threadIdx.x < 64) {
        int o = threadIdx.x;
        blds[o] = bias[ob + o];
        if (POOL) { oscl[o] = osc[ob + o]; oshl[o] = osh[ob + o]; }
    }
    if (NORM_IN) {
        for (int i = threadIdx.x; i < CIN; i += 256) { iscl[i] = isc[i]; ishl[i] = ish[i]; }
    }
    __syncthreads();
    int r = blockIdx.x * 256 + threadIdx.x;
    float acc[64];
#pragma unroll
    for (int o = 0; o < 64; ++o) acc[o] = blds[o];
    const float4* r4 = (const float4*)(Yin + (size_t)r * CIN);
#pragma unroll 4
    for (int cc = 0; cc < CIN / 4; ++cc) {
        float4 x = r4[cc];
        float xs[4] = {x.x, x.y, x.z, x.w};
#pragma unroll
        for (int u = 0; u < 4; ++u) {
            int c = cc * 4 + u;
            float xv = xs[u];
            if (NORM_IN) xv = fmaxf(fmaf(xv, iscl[c], ishl[c]), 0.0f);
            const float* wr = &wlds[c * 64];
#pragma unroll
            for (int o = 0; o < 64; ++o) acc[o] = fmaf(xv, wr[o], acc[o]);
        }
    }
    if (WRITE_Y) {
        float4* yr = (float4*)(Yout + (size_t)r * OTOT + ob);
#pragma unroll
        for (int o4 = 0; o4 < 16; ++o4)
            yr[o4] = make_float4(acc[o4 * 4], acc[o4 * 4 + 1], acc[o4 * 4 + 2], acc[o4 * 4 + 3]);
    }
    if (PARTIALS) {
        int lane = threadIdx.x & 63, wvv = threadIdx.x >> 6;
#pragma unroll
        for (int o = 0; o < 64; ++o) {
            float v = acc[o], v2 = acc[o] * acc[o];
#pragma unroll
            for (int off = 1; off < 64; off <<= 1) { v += __shfl_xor(v, off); v2 += __shfl_xor(v2, off); }
            if (lane == 0) { lsum[wvv][o] = v; lsq[wvv][o] = v2; }
        }
        __syncthreads();
        if (threadIdx.x < 64) {
            int o = threadIdx.x;
            sumP[blockIdx.x * OTOT + ob + o] = lsum[0][o] + lsum[1][o] + lsum[2][o] + lsum[3][o];
            sqP[blockIdx.x * OTOT + ob + o]  = lsq[0][o] + lsq[1][o] + lsq[2][o] + lsq[3][o];
        }
    }
    if (POOL) {
        int b = r >> 15, s = (r >> 5) & (SS - 1);
#pragma unroll
        for (int o = 0; o < 64; ++o) {
            float v = fmaxf(fmaf(acc[o], oscl[o], oshl[o]), 0.0f);
#pragma unroll
            for (int off = 1; off < 32; off <<= 1) v = fmaxf(v, __shfl_xor(v, off));
            if ((threadIdx.x & 31) == 0)
                out1[((size_t)b * O3 + ob + o) * SS + s] = v;
        }
    }
}

// ---------------- finalize BN stats: 512 partials -> scale/shift ---------------
template <int COUT>
__global__ void k_finalize(const float* __restrict__ sumP, const float* __restrict__ sqP,
                           const float* __restrict__ g, const float* __restrict__ beta,
                           float* __restrict__ scale, float* __restrict__ shift) {
    __shared__ float ls[4][COUT], lq[4][COUT];
    int o = threadIdx.x % COUT, q = threadIdx.x / COUT;
    float s = 0.f, qq = 0.f;
    for (int bk = q; bk < 512; bk += 4) { s += sumP[bk * COUT + o]; qq += sqP[bk * COUT + o]; }
    ls[q][o] = s; lq[q][o] = qq;
    __syncthreads();
    if (q == 0) {
        s  = ls[0][o] + ls[1][o] + ls[2][o] + ls[3][o];
        qq = lq[0][o] + lq[1][o] + lq[2][o] + lq[3][o];
        const float inv = 1.0f / (float)RR;
        float mean = s * inv;
        float var = qq * inv - mean * mean;
        float sc = g[o] * rsqrtf(var + EPSF);
        scale[o] = sc;
        shift[o] = beta[o] - mean * sc;
    }
}

extern "C" void kernel_launch(void* const* d_in, const int* in_sizes, int n_in,
                              void* d_out, int out_size, void* d_ws, size_t ws_size,
                              hipStream_t stream) {
    const float* xyz = (const float*)d_in[0];
    const float* pts = (const float*)d_in[1];
    const float* w1  = (const float*)d_in[2];
    const float* b1  = (const float*)d_in[3];
    const float* g1  = (const float*)d_in[4];
    const float* bt1 = (const float*)d_in[5];
    const float* w2  = (const float*)d_in[6];
    const float* b2  = (const float*)d_in[7];
    const float* g2  = (const float*)d_in[8];
    const float* bt2 = (const float*)d_in[9];
    const float* w3  = (const float*)d_in[10];
    const float* b3  = (const float*)d_in[11];
    const float* g3  = (const float*)d_in[12];
    const float* bt3 = (const float*)d_in[13];
    float* out0 = (float*)d_out;                 // (B,3,S)
    float* out1 = out0 + BB * 3 * SS;            // (B,128,S)

    char* wsb = (char*)d_ws;
    size_t off = 0;
    auto alloc = [&](size_t bytes) {
        char* p = wsb + off;
        off += (bytes + 255) & ~(size_t)255;
        return p;
    };
    int*   fps_idx = (int*)alloc((size_t)BB * SS * 4);
    int*   ballidx = (int*)alloc((size_t)RR * 4);
    float* nxyz    = (float*)alloc((size_t)BB * SS * 3 * 4);
    float* sumP    = (float*)alloc((size_t)512 * 128 * 4);
    float* sqP     = (float*)alloc((size_t)512 * 128 * 4);
    float* sc1     = (float*)alloc(128 * 4);
    float* sh1     = (float*)alloc(128 * 4);
    float* sc2     = (float*)alloc(128 * 4);
    float* sh2     = (float*)alloc(128 * 4);
    float* sc3     = (float*)alloc(128 * 4);
    float* sh3     = (float*)alloc(128 * 4);
    float* Y1      = (float*)alloc((size_t)RR * 64 * 4);
    float* Y2      = (float*)alloc((size_t)RR * 64 * 4);
    float* ptsT    = Y2;   // ptsT (16 MB) lives in Y2's slot; Y2 written after gemm1

    k_tr<<<1024, 256, 0, stream>>>(pts, ptsT);
    k_fps<<<BB, FT, 0, stream>>>(xyz, fps_idx);
    k_newxyz<<<16, 256, 0, stream>>>(xyz, fps_idx, out0, nxyz);
    k_ball<<<1024, 256, 0, stream>>>(xyz, nxyz, ballidx);

    k_gemm1<<<512, 256, 0, stream>>>(xyz, ptsT, nxyz, ballidx, w1, b1, Y1, sumP, sqP);
    k_finalize<64><<<1, 256, 0, stream>>>(sumP, sqP, g1, bt1, sc1, sh1);

    k_mlp<64, 64, true, true, true, false><<<dim3(512, 1), 256, 0, stream>>>(
        Y1, w2, b2, sc1, sh1, Y2, sumP, sqP, nullptr, nullptr, nullptr);
    k_finalize<64><<<1, 256, 0, stream>>>(sumP, sqP, g2, bt2, sc2, sh2);

    k_mlp<64, 128, true, false, true, false><<<dim3(512, 2), 256, 0, stream>>>(
        Y2, w3, b3, sc2, sh2, nullptr, sumP, sqP, nullptr, nullptr, nullptr);
    k_finalize<128><<<1, 512, 0, stream>>>(sumP, sqP, g3, bt3, sc3, sh3);

    k_mlp<64, 128, true, false, false, true><<<dim3(512, 2), 256, 0, stream>>>(
        Y2, w3, b3, sc2, sh2, nullptr, nullptr, nullptr, sc3, sh3, out1);
}